// Round 5
// baseline (35.700 us; speedup 1.0000x reference)
//
#include <hip/hip_runtime.h>

// x: (B=8, C=128, T=8, H=56, W=56) fp32
// out[b, t, c, h, w] = w0*x[b,c,t-1,h,w] + w1*x[b,c,t,h,w] + w2*x[b,c,t+1,h,w] + bias
// (zero-padded at t boundaries), out shape (B*T, C, H, W) fp32.
//
// Each thread owns TWO full T-columns (hw and hw+392, half a plane apart so
// every load/store instruction is lane-contiguous): 16 independent loads are
// issued up-front, filter computed in registers, 16 nontemporal stores.

typedef float f32x4 __attribute__((ext_vector_type(4)));

#define B_   8
#define C_   128
#define T_   8
#define HW4  784                       // (56*56)/4 float4 per plane
#define HW2  392                       // half-plane in float4
#define NTH  (B_ * C_ * HW2)           // 401,408 threads (two T-columns each)
#define GRID (NTH / 256)               // 1568 blocks, exact fit

__global__ __launch_bounds__(256) void temporal_interaction_kernel(
    const f32x4* __restrict__ in4,
    const float* __restrict__ cw,
    const float* __restrict__ cb,
    f32x4* __restrict__ out4)
{
    const float w0 = cw[0];
    const float w1 = cw[1];
    const float w2 = cw[2];
    const float bs = cb[0];

    const int i0 = blockIdx.x * 256 + threadIdx.x;   // i0 < NTH
    const int hw = i0 % HW2;
    const int bc = i0 / HW2;          // b*C + c
    const int b  = bc / C_;
    const int c  = bc % C_;

    // input column base: (((b*C + c)*T + 0)*HW4 + hw)
    const f32x4* src = in4 + bc * (T_ * HW4) + hw;

    // load both temporal columns into registers (16 independent loads)
    f32x4 xa[T_], xb[T_];
    #pragma unroll
    for (int t = 0; t < T_; ++t) {
        xa[t] = src[t * HW4];
        xb[t] = src[t * HW4 + HW2];
    }

    // output base for t=0: ((b*T + 0)*C + c)*HW4 + hw; stride C_*HW4 per t
    const int obase = (b * T_ * C_ + c) * HW4 + hw;

    #pragma unroll
    for (int t = 0; t < T_; ++t) {
        const f32x4 pa = (t > 0)      ? xa[t - 1] : (f32x4)(0.f);
        const f32x4 na = (t < T_ - 1) ? xa[t + 1] : (f32x4)(0.f);
        const f32x4 pb = (t > 0)      ? xb[t - 1] : (f32x4)(0.f);
        const f32x4 nb = (t < T_ - 1) ? xb[t + 1] : (f32x4)(0.f);

        f32x4 oa, ob;
        oa.x = fmaf(w0, pa.x, fmaf(w1, xa[t].x, fmaf(w2, na.x, bs)));
        oa.y = fmaf(w0, pa.y, fmaf(w1, xa[t].y, fmaf(w2, na.y, bs)));
        oa.z = fmaf(w0, pa.z, fmaf(w1, xa[t].z, fmaf(w2, na.z, bs)));
        oa.w = fmaf(w0, pa.w, fmaf(w1, xa[t].w, fmaf(w2, na.w, bs)));
        ob.x = fmaf(w0, pb.x, fmaf(w1, xb[t].x, fmaf(w2, nb.x, bs)));
        ob.y = fmaf(w0, pb.y, fmaf(w1, xb[t].y, fmaf(w2, nb.y, bs)));
        ob.z = fmaf(w0, pb.z, fmaf(w1, xb[t].z, fmaf(w2, nb.z, bs)));
        ob.w = fmaf(w0, pb.w, fmaf(w1, xb[t].w, fmaf(w2, nb.w, bs)));

        __builtin_nontemporal_store(oa, &out4[obase + t * (C_ * HW4)]);
        __builtin_nontemporal_store(ob, &out4[obase + t * (C_ * HW4) + HW2]);
    }
}

extern "C" void kernel_launch(void* const* d_in, const int* in_sizes, int n_in,
                              void* d_out, int out_size, void* d_ws, size_t ws_size,
                              hipStream_t stream) {
    const f32x4* in4 = (const f32x4*)d_in[0];
    const float* cw  = (const float*)d_in[1];
    const float* cb  = (const float*)d_in[2];
    f32x4* out4 = (f32x4*)d_out;

    temporal_interaction_kernel<<<GRID, 256, 0, stream>>>(in4, cw, cb, out4);
}

// Round 6
// 34.987 us; speedup vs baseline: 1.0204x; 1.0204x over previous
//
#include <hip/hip_runtime.h>

// x: (B=8, C=128, T=8, H=56, W=56) fp32
// out[b, t, c, h, w] = w0*x[b,c,t-1,h,w] + w1*x[b,c,t,h,w] + w2*x[b,c,t+1,h,w] + bias
// (zero-padded at t boundaries), out shape (B*T, C, H, W) fp32.
//
// Round-4 structure (best: 34.9 us): one T-column per thread, 8 loads up-front,
// filter in registers, 8 coalesced stores. This round: REGULAR stores (no nt)
// so the output can live write-back in the 256MB L3 (in+out = 206MB fits).

typedef float f32x4 __attribute__((ext_vector_type(4)));

#define B_   8
#define C_   128
#define T_   8
#define HW4  784                       // (56*56)/4 float4 per plane
#define NTH  (B_ * C_ * HW4)           // 802,816 threads (one per T-column)
#define GRID (NTH / 256)               // 3136 blocks, exact fit

__global__ __launch_bounds__(256) void temporal_interaction_kernel(
    const f32x4* __restrict__ in4,
    const float* __restrict__ cw,
    const float* __restrict__ cb,
    f32x4* __restrict__ out4)
{
    const float w0 = cw[0];
    const float w1 = cw[1];
    const float w2 = cw[2];
    const float bs = cb[0];

    const int i0 = blockIdx.x * 256 + threadIdx.x;   // i0 < NTH
    const int hw = i0 % HW4;
    const int bc = i0 / HW4;          // b*C + c
    const int b  = bc / C_;
    const int c  = bc % C_;

    // input column base: (((b*C + c)*T + 0)*HW4 + hw)
    const f32x4* src = in4 + bc * (T_ * HW4) + hw;

    // load the whole temporal column into registers (8 independent loads)
    f32x4 x[T_];
    #pragma unroll
    for (int t = 0; t < T_; ++t) x[t] = src[t * HW4];

    // output base for t=0: ((b*T + 0)*C + c)*HW4 + hw; stride C_*HW4 per t
    const int obase = (b * T_ * C_ + c) * HW4 + hw;

    #pragma unroll
    for (int t = 0; t < T_; ++t) {
        const f32x4 prv = (t > 0)      ? x[t - 1] : (f32x4)(0.f);
        const f32x4 nxt = (t < T_ - 1) ? x[t + 1] : (f32x4)(0.f);

        f32x4 o;
        o.x = fmaf(w0, prv.x, fmaf(w1, x[t].x, fmaf(w2, nxt.x, bs)));
        o.y = fmaf(w0, prv.y, fmaf(w1, x[t].y, fmaf(w2, nxt.y, bs)));
        o.z = fmaf(w0, prv.z, fmaf(w1, x[t].z, fmaf(w2, nxt.z, bs)));
        o.w = fmaf(w0, prv.w, fmaf(w1, x[t].w, fmaf(w2, nxt.w, bs)));

        out4[obase + t * (C_ * HW4)] = o;   // regular store: L3 write-back
    }
}

extern "C" void kernel_launch(void* const* d_in, const int* in_sizes, int n_in,
                              void* d_out, int out_size, void* d_ws, size_t ws_size,
                              hipStream_t stream) {
    const f32x4* in4 = (const f32x4*)d_in[0];
    const float* cw  = (const float*)d_in[1];
    const float* cb  = (const float*)d_in[2];
    f32x4* out4 = (f32x4*)d_out;

    temporal_interaction_kernel<<<GRID, 256, 0, stream>>>(in4, cw, cb, out4);
}